// Round 4
// baseline (78369.916 us; speedup 1.0000x reference)
//
#include <hip/hip_runtime.h>

#define T_DIM 2048
#define B_DIM 16
#define H_DIM 1024
#define C3    3072
#define NBLK  256

// ---------------- ws layout (float elements) ----------------
// x    : [T][B][3072]  normalized input projections (384 MB)
// msum : [2][1024]     column sums of w_hh groups
// hbuf : [2][16][1024] ping-pong hidden state
// bar  : 16 ints       barrier counters (leaf[8], root, go)
static const size_t X_ELEMS = (size_t)T_DIM * B_DIM * C3;
static const size_t MS_OFF  = X_ELEMS;
static const size_t HB_OFF  = MS_OFF + 2048;
static const size_t BAR_OFF = HB_OFF + 2ull * B_DIM * H_DIM;

// ============ K1: column sums of w_hh per LN group ============
__global__ __launch_bounds__(256) void k_colsum(const float* __restrict__ w_hh,
                                                float* __restrict__ msum)
{
    int k  = blockIdx.x * 256 + threadIdx.x;   // gridDim.x == 4
    int rc = blockIdx.y;                       // 0..11 row chunks of 256
    const float* p = w_hh + (size_t)rc * 256 * H_DIM + k;
    float s = 0.f;
    #pragma unroll 8
    for (int r = 0; r < 256; ++r) s += p[(size_t)r * H_DIM];
    atomicAdd(&msum[(rc < 8 ? 0 : 1) * H_DIM + k], s);
}

// ============ K2: proj = xs @ w_ih^T , f32, out layout [T][B][3072] ============
#define BM 128
#define BN 64
#define BK 32
__global__ __launch_bounds__(256) void k_gemm(const float* __restrict__ A,
                                              const float* __restrict__ Bw,
                                              float* __restrict__ X)
{
    __shared__ float As[BK][BM + 4];
    __shared__ float Bs[BK][BN + 4];
    int n0 = blockIdx.x * BN;
    int m0 = blockIdx.y * BM;
    int tid = threadIdx.x;
    int tx = tid & 15, ty = tid >> 4;
    float acc[8][4];
    #pragma unroll
    for (int i = 0; i < 8; ++i)
        #pragma unroll
        for (int j = 0; j < 4; ++j) acc[i][j] = 0.f;

    for (int k0 = 0; k0 < 1024; k0 += BK) {
        #pragma unroll
        for (int p = 0; p < 4; ++p) {
            int id = tid + p * 256;
            int r = id >> 3, c4 = (id & 7) * 4;
            float4 v = *(const float4*)&A[(size_t)(m0 + r) * 1024 + k0 + c4];
            As[c4 + 0][r] = v.x; As[c4 + 1][r] = v.y;
            As[c4 + 2][r] = v.z; As[c4 + 3][r] = v.w;
        }
        #pragma unroll
        for (int p = 0; p < 2; ++p) {
            int id = tid + p * 256;
            int r = id >> 3, c4 = (id & 7) * 4;
            float4 v = *(const float4*)&Bw[(size_t)(n0 + r) * 1024 + k0 + c4];
            Bs[c4 + 0][r] = v.x; Bs[c4 + 1][r] = v.y;
            Bs[c4 + 2][r] = v.z; Bs[c4 + 3][r] = v.w;
        }
        __syncthreads();
        #pragma unroll
        for (int kk = 0; kk < BK; ++kk) {
            float4 a0 = *(const float4*)&As[kk][ty * 8];
            float4 a1 = *(const float4*)&As[kk][ty * 8 + 4];
            float4 b0 = *(const float4*)&Bs[kk][tx * 4];
            float a[8] = {a0.x, a0.y, a0.z, a0.w, a1.x, a1.y, a1.z, a1.w};
            float b[4] = {b0.x, b0.y, b0.z, b0.w};
            #pragma unroll
            for (int i = 0; i < 8; ++i)
                #pragma unroll
                for (int j = 0; j < 4; ++j) acc[i][j] += a[i] * b[j];
        }
        __syncthreads();
    }
    #pragma unroll
    for (int i = 0; i < 8; ++i) {
        int m = m0 + ty * 8 + i;
        int tt = m & (T_DIM - 1), bb = m >> 11;
        float4 v = make_float4(acc[i][0], acc[i][1], acc[i][2], acc[i][3]);
        *(float4*)&X[((size_t)tt * B_DIM + bb) * C3 + n0 + tx * 4] = v;
    }
}

// ============ K3: in-place _ln_x per 3072-row ============
__device__ __forceinline__ float block_sum_256(float v, float* sb)
{
    #pragma unroll
    for (int o = 32; o > 0; o >>= 1) v += __shfl_down(v, o, 64);
    int lane = threadIdx.x & 63, wid = threadIdx.x >> 6;
    if (lane == 0) sb[wid] = v;
    __syncthreads();
    float r = (sb[0] + sb[1]) + (sb[2] + sb[3]);
    __syncthreads();
    return r;
}

__global__ __launch_bounds__(256) void k_ln(float* __restrict__ X,
                                            const float* __restrict__ gamma,
                                            const float* __restrict__ beta)
{
    __shared__ float sb[4];
    float* p = X + (size_t)blockIdx.x * C3;
    int tid = threadIdx.x;
    float v[8], w[4];
    float4 t0 = *(float4*)&p[tid * 8];
    float4 t1 = *(float4*)&p[tid * 8 + 4];
    v[0]=t0.x; v[1]=t0.y; v[2]=t0.z; v[3]=t0.w;
    v[4]=t1.x; v[5]=t1.y; v[6]=t1.z; v[7]=t1.w;
    float4 t2 = *(float4*)&p[2048 + tid * 4];
    w[0]=t2.x; w[1]=t2.y; w[2]=t2.z; w[3]=t2.w;

    float s = 0.f;
    #pragma unroll
    for (int i = 0; i < 8; ++i) s += v[i];
    float mean = block_sum_256(s, sb) * (1.f / 2048.f);
    float ss = 0.f;
    #pragma unroll
    for (int i = 0; i < 8; ++i) { float d = v[i] - mean; ss += d * d; }
    float inv = rsqrtf(block_sum_256(ss, sb) * (1.f / 2047.f));
    #pragma unroll
    for (int i = 0; i < 8; ++i) {
        int c = tid * 8 + i;
        v[i] = gamma[c] * (v[i] - mean) * inv + beta[c];
    }
    *(float4*)&p[tid * 8]     = make_float4(v[0], v[1], v[2], v[3]);
    *(float4*)&p[tid * 8 + 4] = make_float4(v[4], v[5], v[6], v[7]);

    float sn = (w[0] + w[1]) + (w[2] + w[3]);
    float mn = block_sum_256(sn, sb) * (1.f / 1024.f);
    float ssn = 0.f;
    #pragma unroll
    for (int i = 0; i < 4; ++i) { float d = w[i] - mn; ssn += d * d; }
    float invn = rsqrtf(block_sum_256(ssn, sb) * (1.f / 1023.f));
    #pragma unroll
    for (int i = 0; i < 4; ++i) {
        int c = 2048 + tid * 4 + i;
        w[i] = gamma[c] * (w[i] - mn) * invn + beta[c];
    }
    *(float4*)&p[2048 + tid * 4] = make_float4(w[0], w[1], w[2], w[3]);
}

// ============ K4: persistent weight-stationary scan ============
// 256 blocks x 1024 threads, 1 block/CU (LDS 66KB, VGPR<=128 via launch_bounds).
// Block bid owns j in [bid*4, bid*4+4), all 3 gates -> 12 channels of W''.
// Thread (cg 0..3, bg 0..3, ks 0..63): 3 channels x 4 batches x 16 k in regs.
// XOR swizzle for h in LDS: word k stored at k ^ (((k>>4)&7)<<2)  (bijective,
// 8 consecutive ks-lanes hit all 8 bank-quads -> conflict-free ds_read_b128).
__device__ __forceinline__ int swz(int k) { return k ^ (((k >> 4) & 7) << 2); }

#define FMA_E(comp, e)                                                      \
    { float w0_ = w[0][kq + e], w1_ = w[1][kq + e], w2_ = w[2][kq + e];     \
      acc[0][0] += w0_ * hv0.comp; acc[0][1] += w0_ * hv1.comp;             \
      acc[0][2] += w0_ * hv2.comp; acc[0][3] += w0_ * hv3.comp;             \
      acc[1][0] += w1_ * hv0.comp; acc[1][1] += w1_ * hv1.comp;             \
      acc[1][2] += w1_ * hv2.comp; acc[1][3] += w1_ * hv3.comp;             \
      acc[2][0] += w2_ * hv0.comp; acc[2][1] += w2_ * hv1.comp;             \
      acc[2][2] += w2_ * hv2.comp; acc[2][3] += w2_ * hv3.comp; }

__global__ __launch_bounds__(1024, 4) void k_scan(
    const float* __restrict__ X,
    const float* __restrict__ w_hh,
    const float* __restrict__ g_hh,
    const float* __restrict__ b_hh,
    const float* __restrict__ msum,
    const float* __restrict__ h0,
    float* __restrict__ hbuf,
    float* __restrict__ ys,
    float* __restrict__ hfin,
    int* __restrict__ bar)
{
    __shared__ float hs[16 * 1024];
    __shared__ float dotl[12][17];

    int tid = threadIdx.x;
    int bid = blockIdx.x;
    int cg = tid >> 8, bg = (tid >> 6) & 3, ks = tid & 63;
    int js = bid * 4;

    // ---- load W'' = gamma*(w_hh - colmean) into registers (once) ----
    float w[3][16];
    #pragma unroll
    for (int ci = 0; ci < 3; ++ci) {
        int lc = cg * 3 + ci;
        int gate = lc >> 2, jl = lc & 3;
        int c = gate * H_DIM + js + jl;
        int grp = (gate < 2) ? 0 : 1;
        float scale = grp ? (1.f / 1024.f) : (1.f / 2048.f);
        float gm = g_hh[c];
        const float* wr = w_hh + (size_t)c * H_DIM;
        #pragma unroll
        for (int q = 0; q < 16; ++q) {
            int k = ks * 16 + q;
            w[ci][q] = gm * (wr[k] - msum[grp * H_DIM + k] * scale);
        }
    }

    // gate-phase constants
    int bl = tid & 15, jl4 = tid >> 4;            // valid when tid < 64
    float br = 0.f, bz = 0.f, bn = 0.f;
    if (tid < 64) {
        br = b_hh[js + jl4];
        bz = b_hh[H_DIM + js + jl4];
        bn = b_hh[2 * H_DIM + js + jl4];
    }

    for (int t = 0; t < T_DIM; ++t) {
        // X[t] prefetch (latency hidden under stage+dot phases)
        float xr = 0.f, xz = 0.f, xn = 0.f;
        if (tid < 64) {
            const float* xp = X + ((size_t)t * B_DIM + bl) * C3 + js + jl4;
            xr = xp[0]; xz = xp[H_DIM]; xn = xp[2 * H_DIM];
        }

        // ---- stage h into LDS (swizzled) ----
        const float* h_in = t ? (hbuf + (size_t)(t & 1) * B_DIM * H_DIM) : h0;
        #pragma unroll
        for (int q = 0; q < 4; ++q) {
            int f = tid + q * 1024;               // float4 index, 4096 total
            int b = f >> 8, k = (f & 255) * 4;
            float4 v = *(const float4*)&h_in[(size_t)b * H_DIM + k];
            *(float4*)&hs[b * H_DIM + swz(k)] = v;
        }
        __syncthreads();

        // ---- partial dots: 3ch x 4b x 16k ----
        float acc[3][4];
        #pragma unroll
        for (int i = 0; i < 3; ++i)
            #pragma unroll
            for (int j = 0; j < 4; ++j) acc[i][j] = 0.f;

        #pragma unroll
        for (int kk = 0; kk < 4; ++kk) {
            int kq = kk * 4;
            int kw = (ks * 16 + kq) ^ ((ks & 7) << 2);
            float4 hv0 = *(const float4*)&hs[(bg * 4 + 0) * H_DIM + kw];
            float4 hv1 = *(const float4*)&hs[(bg * 4 + 1) * H_DIM + kw];
            float4 hv2 = *(const float4*)&hs[(bg * 4 + 2) * H_DIM + kw];
            float4 hv3 = *(const float4*)&hs[(bg * 4 + 3) * H_DIM + kw];
            FMA_E(x, 0) FMA_E(y, 1) FMA_E(z, 2) FMA_E(w, 3)
        }

        // ---- butterfly reduce over ks lanes ----
        #pragma unroll
        for (int m = 1; m <= 32; m <<= 1)
            #pragma unroll
            for (int ci = 0; ci < 3; ++ci)
                #pragma unroll
                for (int bi = 0; bi < 4; ++bi)
                    acc[ci][bi] += __shfl_xor(acc[ci][bi], m, 64);
        if (ks == 0) {
            #pragma unroll
            for (int ci = 0; ci < 3; ++ci)
                #pragma unroll
                for (int bi = 0; bi < 4; ++bi)
                    dotl[cg * 3 + ci][bg * 4 + bi] = acc[ci][bi];
        }
        __syncthreads();

        // ---- gates: 4 j x 16 b ----
        float* h_out = hbuf + (size_t)((t + 1) & 1) * B_DIM * H_DIM;
        if (tid < 64) {
            int j = js + jl4;
            float dr = dotl[jl4][bl] + br;
            float dz = dotl[4 + jl4][bl] + bz;
            float dn = dotl[8 + jl4][bl] + bn;
            float r = 1.f / (1.f + __expf(-(xr + dr)));
            float z = 1.f / (1.f + __expf(-(xz + dz)));
            float n = tanhf(xn + r * dn);
            float hold = hs[bl * H_DIM + swz(j)];
            float hnew = (1.f - z) * n + z * hold;
            h_out[(size_t)bl * H_DIM + j] = hnew;
            ys[((size_t)bl * T_DIM + t) * H_DIM + j] = hnew;
            if (t == T_DIM - 1) hfin[(size_t)bl * H_DIM + j] = hnew;
        }
        __syncthreads();   // drain stores (each thread waits own vmcnt)

        // ---- grid barrier: 2-level monotone counters, release/acquire ----
        if (tid == 0) {
            __threadfence();                       // release: wb L2
            int g = bid >> 5;
            int a = __hip_atomic_fetch_add(&bar[g], 1, __ATOMIC_ACQ_REL,
                                           __HIP_MEMORY_SCOPE_AGENT);
            if (a == 32 * (t + 1) - 1) {
                int rt = __hip_atomic_fetch_add(&bar[8], 1, __ATOMIC_ACQ_REL,
                                                __HIP_MEMORY_SCOPE_AGENT);
                if (rt == 8 * (t + 1) - 1)
                    __hip_atomic_store(&bar[9], t + 1, __ATOMIC_RELEASE,
                                       __HIP_MEMORY_SCOPE_AGENT);
            }
            while (__hip_atomic_load(&bar[9], __ATOMIC_RELAXED,
                                     __HIP_MEMORY_SCOPE_AGENT) < t + 1)
                __builtin_amdgcn_s_sleep(1);
            __threadfence();                       // acquire: inv caches
        }
        __syncthreads();
    }
}

extern "C" void kernel_launch(void* const* d_in, const int* in_sizes, int n_in,
                              void* d_out, int out_size, void* d_ws, size_t ws_size,
                              hipStream_t stream)
{
    (void)in_sizes; (void)n_in; (void)out_size; (void)ws_size;
    const float* xs   = (const float*)d_in[0];
    const float* h0   = (const float*)d_in[1];
    const float* w_ih = (const float*)d_in[2];
    const float* w_hh = (const float*)d_in[3];
    const float* b_ih = (const float*)d_in[4];
    const float* b_hh = (const float*)d_in[5];
    const float* g_ih = (const float*)d_in[6];
    const float* g_hh = (const float*)d_in[7];
    float* out = (float*)d_out;
    float* ws  = (float*)d_ws;

    float* x    = ws;
    float* msum = ws + MS_OFF;
    float* hbuf = ws + HB_OFF;
    int*   bar  = (int*)(ws + BAR_OFF);

    // zero msum + hbuf + barrier counters (ws is poisoned before every call)
    hipMemsetAsync(msum, 0, (2048 + 2ull * B_DIM * H_DIM + 16) * sizeof(float),
                   stream);
    k_colsum<<<dim3(4, 12), 256, 0, stream>>>(w_hh, msum);
    k_gemm<<<dim3(48, 256), 256, 0, stream>>>(xs, w_ih, x);
    k_ln<<<T_DIM * B_DIM, 256, 0, stream>>>(x, g_ih, b_ih);
    k_scan<<<NBLK, 1024, 0, stream>>>(x, w_hh, g_hh, b_hh, msum, h0, hbuf,
                                      out, out + (size_t)B_DIM * T_DIM * H_DIM,
                                      bar);
}

// Round 5
// 73138.562 us; speedup vs baseline: 1.0715x; 1.0715x over previous
//
#include <hip/hip_runtime.h>

#define T_DIM 2048
#define B_DIM 16
#define H_DIM 1024
#define C3    3072
#define NBLK  256

// ---------------- ws layout (float elements) ----------------
// x    : [T][B][3072]  normalized input projections (384 MB)
// msum : [2][1024]     column sums of w_hh groups
// hbuf : [2][16][1024] ping-pong hidden state (accessed ONLY via agent atomics)
// bar  : 16 ints       barrier counters (leaf[8], root, go)
static const size_t X_ELEMS = (size_t)T_DIM * B_DIM * C3;
static const size_t MS_OFF  = X_ELEMS;
static const size_t HB_OFF  = MS_OFF + 2048;
static const size_t BAR_OFF = HB_OFF + 2ull * B_DIM * H_DIM;

// ============ K1: column sums of w_hh per LN group ============
__global__ __launch_bounds__(256) void k_colsum(const float* __restrict__ w_hh,
                                                float* __restrict__ msum)
{
    int k  = blockIdx.x * 256 + threadIdx.x;   // gridDim.x == 4
    int rc = blockIdx.y;                       // 0..11 row chunks of 256
    const float* p = w_hh + (size_t)rc * 256 * H_DIM + k;
    float s = 0.f;
    #pragma unroll 8
    for (int r = 0; r < 256; ++r) s += p[(size_t)r * H_DIM];
    atomicAdd(&msum[(rc < 8 ? 0 : 1) * H_DIM + k], s);
}

// ============ K2: proj = xs @ w_ih^T , f32, out layout [T][B][3072] ============
#define BM 128
#define BN 64
#define BK 32
__global__ __launch_bounds__(256) void k_gemm(const float* __restrict__ A,
                                              const float* __restrict__ Bw,
                                              float* __restrict__ X)
{
    __shared__ float As[BK][BM + 4];
    __shared__ float Bs[BK][BN + 4];
    int n0 = blockIdx.x * BN;
    int m0 = blockIdx.y * BM;
    int tid = threadIdx.x;
    int tx = tid & 15, ty = tid >> 4;
    float acc[8][4];
    #pragma unroll
    for (int i = 0; i < 8; ++i)
        #pragma unroll
        for (int j = 0; j < 4; ++j) acc[i][j] = 0.f;

    for (int k0 = 0; k0 < 1024; k0 += BK) {
        #pragma unroll
        for (int p = 0; p < 4; ++p) {
            int id = tid + p * 256;
            int r = id >> 3, c4 = (id & 7) * 4;
            float4 v = *(const float4*)&A[(size_t)(m0 + r) * 1024 + k0 + c4];
            As[c4 + 0][r] = v.x; As[c4 + 1][r] = v.y;
            As[c4 + 2][r] = v.z; As[c4 + 3][r] = v.w;
        }
        #pragma unroll
        for (int p = 0; p < 2; ++p) {
            int id = tid + p * 256;
            int r = id >> 3, c4 = (id & 7) * 4;
            float4 v = *(const float4*)&Bw[(size_t)(n0 + r) * 1024 + k0 + c4];
            Bs[c4 + 0][r] = v.x; Bs[c4 + 1][r] = v.y;
            Bs[c4 + 2][r] = v.z; Bs[c4 + 3][r] = v.w;
        }
        __syncthreads();
        #pragma unroll
        for (int kk = 0; kk < BK; ++kk) {
            float4 a0 = *(const float4*)&As[kk][ty * 8];
            float4 a1 = *(const float4*)&As[kk][ty * 8 + 4];
            float4 b0 = *(const float4*)&Bs[kk][tx * 4];
            float a[8] = {a0.x, a0.y, a0.z, a0.w, a1.x, a1.y, a1.z, a1.w};
            float b[4] = {b0.x, b0.y, b0.z, b0.w};
            #pragma unroll
            for (int i = 0; i < 8; ++i)
                #pragma unroll
                for (int j = 0; j < 4; ++j) acc[i][j] += a[i] * b[j];
        }
        __syncthreads();
    }
    #pragma unroll
    for (int i = 0; i < 8; ++i) {
        int m = m0 + ty * 8 + i;
        int tt = m & (T_DIM - 1), bb = m >> 11;
        float4 v = make_float4(acc[i][0], acc[i][1], acc[i][2], acc[i][3]);
        *(float4*)&X[((size_t)tt * B_DIM + bb) * C3 + n0 + tx * 4] = v;
    }
}

// ============ K3: in-place _ln_x per 3072-row ============
__device__ __forceinline__ float block_sum_256(float v, float* sb)
{
    #pragma unroll
    for (int o = 32; o > 0; o >>= 1) v += __shfl_down(v, o, 64);
    int lane = threadIdx.x & 63, wid = threadIdx.x >> 6;
    if (lane == 0) sb[wid] = v;
    __syncthreads();
    float r = (sb[0] + sb[1]) + (sb[2] + sb[3]);
    __syncthreads();
    return r;
}

__global__ __launch_bounds__(256) void k_ln(float* __restrict__ X,
                                            const float* __restrict__ gamma,
                                            const float* __restrict__ beta)
{
    __shared__ float sb[4];
    float* p = X + (size_t)blockIdx.x * C3;
    int tid = threadIdx.x;
    float v[8], w[4];
    float4 t0 = *(float4*)&p[tid * 8];
    float4 t1 = *(float4*)&p[tid * 8 + 4];
    v[0]=t0.x; v[1]=t0.y; v[2]=t0.z; v[3]=t0.w;
    v[4]=t1.x; v[5]=t1.y; v[6]=t1.z; v[7]=t1.w;
    float4 t2 = *(float4*)&p[2048 + tid * 4];
    w[0]=t2.x; w[1]=t2.y; w[2]=t2.z; w[3]=t2.w;

    float s = 0.f;
    #pragma unroll
    for (int i = 0; i < 8; ++i) s += v[i];
    float mean = block_sum_256(s, sb) * (1.f / 2048.f);
    float ss = 0.f;
    #pragma unroll
    for (int i = 0; i < 8; ++i) { float d = v[i] - mean; ss += d * d; }
    float inv = rsqrtf(block_sum_256(ss, sb) * (1.f / 2047.f));
    #pragma unroll
    for (int i = 0; i < 8; ++i) {
        int c = tid * 8 + i;
        v[i] = gamma[c] * (v[i] - mean) * inv + beta[c];
    }
    *(float4*)&p[tid * 8]     = make_float4(v[0], v[1], v[2], v[3]);
    *(float4*)&p[tid * 8 + 4] = make_float4(v[4], v[5], v[6], v[7]);

    float sn = (w[0] + w[1]) + (w[2] + w[3]);
    float mn = block_sum_256(sn, sb) * (1.f / 1024.f);
    float ssn = 0.f;
    #pragma unroll
    for (int i = 0; i < 4; ++i) { float d = w[i] - mn; ssn += d * d; }
    float invn = rsqrtf(block_sum_256(ssn, sb) * (1.f / 1023.f));
    #pragma unroll
    for (int i = 0; i < 4; ++i) {
        int c = 2048 + tid * 4 + i;
        w[i] = gamma[c] * (w[i] - mn) * invn + beta[c];
    }
    *(float4*)&p[2048 + tid * 4] = make_float4(w[0], w[1], w[2], w[3]);
}

// ============ K4: persistent weight-stationary scan ============
// 256 blocks x 1024 threads, 1 block/CU. Coherence protocol (no fences, no inv):
//  - h ping-pong accessed ONLY via agent-scope RELAXED atomics -> write-through
//    to the shared LLC on store, L2-bypass on load. h never lives in any L2.
//  - barrier counters: RELEASE-only fetch_adds (vmcnt drain + wb, no inv);
//    go-flag poll is a RELAXED agent load; in-order issue after the dependent
//    branch orders subsequent h loads. X/ys stay normally cached in L2.
__device__ __forceinline__ int swz(int k) { return k ^ (((k >> 4) & 7) << 2); }

#define FMA_E(comp, e)                                                      \
    { float w0_ = w[0][kq + e], w1_ = w[1][kq + e], w2_ = w[2][kq + e];     \
      acc[0][0] += w0_ * hv0.comp; acc[0][1] += w0_ * hv1.comp;             \
      acc[0][2] += w0_ * hv2.comp; acc[0][3] += w0_ * hv3.comp;             \
      acc[1][0] += w1_ * hv0.comp; acc[1][1] += w1_ * hv1.comp;             \
      acc[1][2] += w1_ * hv2.comp; acc[1][3] += w1_ * hv3.comp;             \
      acc[2][0] += w2_ * hv0.comp; acc[2][1] += w2_ * hv1.comp;             \
      acc[2][2] += w2_ * hv2.comp; acc[2][3] += w2_ * hv3.comp; }

__global__ __launch_bounds__(1024, 4) void k_scan(
    const float* __restrict__ X,
    const float* __restrict__ w_hh,
    const float* __restrict__ g_hh,
    const float* __restrict__ b_hh,
    const float* __restrict__ msum,
    const float* __restrict__ h0,
    float* __restrict__ hbuf,
    float* __restrict__ ys,
    float* __restrict__ hfin,
    int* __restrict__ bar)
{
    __shared__ float hs[16 * 1024];
    __shared__ float dotl[12][17];

    int tid = threadIdx.x;
    int bid = blockIdx.x;
    int cg = tid >> 8, bg = (tid >> 6) & 3, ks = tid & 63;
    int js = bid * 4;

    // ---- load W'' = gamma*(w_hh - colmean) into registers (once) ----
    float w[3][16];
    #pragma unroll
    for (int ci = 0; ci < 3; ++ci) {
        int lc = cg * 3 + ci;
        int gate = lc >> 2, jl = lc & 3;
        int c = gate * H_DIM + js + jl;
        int grp = (gate < 2) ? 0 : 1;
        float scale = grp ? (1.f / 1024.f) : (1.f / 2048.f);
        float gm = g_hh[c];
        const float* wr = w_hh + (size_t)c * H_DIM;
        #pragma unroll
        for (int q = 0; q < 16; ++q) {
            int k = ks * 16 + q;
            w[ci][q] = gm * (wr[k] - msum[grp * H_DIM + k] * scale);
        }
    }

    // gate-phase constants
    int bl = tid & 15, jl4 = tid >> 4;            // valid when tid < 64
    float br = 0.f, bz = 0.f, bn = 0.f;
    if (tid < 64) {
        br = b_hh[js + jl4];
        bz = b_hh[H_DIM + js + jl4];
        bn = b_hh[2 * H_DIM + js + jl4];
    }

    for (int t = 0; t < T_DIM; ++t) {
        // X[t] prefetch (normal cached loads; latency hidden under stage+dot)
        float xr = 0.f, xz = 0.f, xn = 0.f;
        if (tid < 64) {
            const float* xp = X + ((size_t)t * B_DIM + bl) * C3 + js + jl4;
            xr = xp[0]; xz = xp[H_DIM]; xn = xp[2 * H_DIM];
        }

        // ---- stage h into LDS (agent-atomic loads, swizzled scalar writes) ----
        const float* h_in = t ? (hbuf + (size_t)(t & 1) * B_DIM * H_DIM) : h0;
        int sk = swz(tid);
        #pragma unroll
        for (int q = 0; q < 16; ++q) {
            float v = __hip_atomic_load((float*)(h_in + q * H_DIM + tid),
                                        __ATOMIC_RELAXED,
                                        __HIP_MEMORY_SCOPE_AGENT);
            hs[q * H_DIM + sk] = v;
        }
        __syncthreads();

        // ---- partial dots: 3ch x 4b x 16k ----
        float acc[3][4];
        #pragma unroll
        for (int i = 0; i < 3; ++i)
            #pragma unroll
            for (int j = 0; j < 4; ++j) acc[i][j] = 0.f;

        #pragma unroll
        for (int kk = 0; kk < 4; ++kk) {
            int kq = kk * 4;
            int kw = (ks * 16 + kq) ^ ((ks & 7) << 2);
            float4 hv0 = *(const float4*)&hs[(bg * 4 + 0) * H_DIM + kw];
            float4 hv1 = *(const float4*)&hs[(bg * 4 + 1) * H_DIM + kw];
            float4 hv2 = *(const float4*)&hs[(bg * 4 + 2) * H_DIM + kw];
            float4 hv3 = *(const float4*)&hs[(bg * 4 + 3) * H_DIM + kw];
            FMA_E(x, 0) FMA_E(y, 1) FMA_E(z, 2) FMA_E(w, 3)
        }

        // ---- butterfly reduce over ks lanes ----
        #pragma unroll
        for (int m = 1; m <= 32; m <<= 1)
            #pragma unroll
            for (int ci = 0; ci < 3; ++ci)
                #pragma unroll
                for (int bi = 0; bi < 4; ++bi)
                    acc[ci][bi] += __shfl_xor(acc[ci][bi], m, 64);
        if (ks == 0) {
            #pragma unroll
            for (int ci = 0; ci < 3; ++ci)
                #pragma unroll
                for (int bi = 0; bi < 4; ++bi)
                    dotl[cg * 3 + ci][bg * 4 + bi] = acc[ci][bi];
        }
        __syncthreads();

        // ---- gates: 4 j x 16 b (all in wave 0) ----
        float* h_out = hbuf + (size_t)((t + 1) & 1) * B_DIM * H_DIM;
        if (tid < 64) {
            int j = js + jl4;
            float dr = dotl[jl4][bl] + br;
            float dz = dotl[4 + jl4][bl] + bz;
            float dn = dotl[8 + jl4][bl] + bn;
            float r = 1.f / (1.f + __expf(-(xr + dr)));
            float z = 1.f / (1.f + __expf(-(xz + dz)));
            float n = tanhf(xn + r * dn);
            float hold = hs[bl * H_DIM + swz(j)];
            float hnew = (1.f - z) * n + z * hold;
            __hip_atomic_store(&h_out[(size_t)bl * H_DIM + j], hnew,
                               __ATOMIC_RELAXED, __HIP_MEMORY_SCOPE_AGENT);
            ys[((size_t)bl * T_DIM + t) * H_DIM + j] = hnew;
            if (t == T_DIM - 1) hfin[(size_t)bl * H_DIM + j] = hnew;
        }
        __syncthreads();

        // ---- grid barrier: 2-level monotone counters, release-only ----
        if (tid == 0) {
            int g = bid >> 5;
            // RELEASE: drains wave-0's vmcnt (h stores to LLC complete), no inv
            int a = __hip_atomic_fetch_add(&bar[g], 1, __ATOMIC_RELEASE,
                                           __HIP_MEMORY_SCOPE_AGENT);
            if (a == 32 * (t + 1) - 1) {
                int rt = __hip_atomic_fetch_add(&bar[8], 1, __ATOMIC_RELEASE,
                                                __HIP_MEMORY_SCOPE_AGENT);
                if (rt == 8 * (t + 1) - 1)
                    __hip_atomic_store(&bar[9], t + 1, __ATOMIC_RELEASE,
                                       __HIP_MEMORY_SCOPE_AGENT);
            }
            while (__hip_atomic_load(&bar[9], __ATOMIC_RELAXED,
                                     __HIP_MEMORY_SCOPE_AGENT) < t + 1)
                __builtin_amdgcn_s_sleep(1);
        }
        __syncthreads();
    }
}

extern "C" void kernel_launch(void* const* d_in, const int* in_sizes, int n_in,
                              void* d_out, int out_size, void* d_ws, size_t ws_size,
                              hipStream_t stream)
{
    (void)in_sizes; (void)n_in; (void)out_size; (void)ws_size;
    const float* xs   = (const float*)d_in[0];
    const float* h0   = (const float*)d_in[1];
    const float* w_ih = (const float*)d_in[2];
    const float* w_hh = (const float*)d_in[3];
    const float* b_ih = (const float*)d_in[4];
    const float* b_hh = (const float*)d_in[5];
    const float* g_ih = (const float*)d_in[6];
    const float* g_hh = (const float*)d_in[7];
    float* out = (float*)d_out;
    float* ws  = (float*)d_ws;

    float* x    = ws;
    float* msum = ws + MS_OFF;
    float* hbuf = ws + HB_OFF;
    int*   bar  = (int*)(ws + BAR_OFF);

    // zero msum + hbuf + barrier counters (ws is poisoned before every call;
    // kernel-boundary cache flush makes these lines clean before k_scan)
    hipMemsetAsync(msum, 0, (2048 + 2ull * B_DIM * H_DIM + 16) * sizeof(float),
                   stream);
    k_colsum<<<dim3(4, 12), 256, 0, stream>>>(w_hh, msum);
    k_gemm<<<dim3(48, 256), 256, 0, stream>>>(xs, w_ih, x);
    k_ln<<<T_DIM * B_DIM, 256, 0, stream>>>(x, g_ih, b_ih);
    k_scan<<<NBLK, 1024, 0, stream>>>(x, w_hh, g_hh, b_hh, msum, h0, hbuf,
                                      out, out + (size_t)B_DIM * T_DIM * H_DIM,
                                      bar);
}

// Round 6
// 58910.901 us; speedup vs baseline: 1.3303x; 1.2415x over previous
//
#include <hip/hip_runtime.h>

#define T_DIM 2048
#define B_DIM 16
#define H_DIM 1024
#define C3    3072
#define NBLK  256

// ---------------- ws layout (float elements) ----------------
// x     : [T][B][3072]  normalized input projections (384 MB)
// msum  : [2][1024]     column sums of w_hh groups
// hbuf  : [2][16][1024] ping-pong hidden state (agent atomics only)
// flags : 256 slots x 32 ints (128B/slot)  per-block arrival stamps
// go    : 256 slots x 32 ints (128B/slot)  per-block release stamps
static const size_t X_ELEMS = (size_t)T_DIM * B_DIM * C3;
static const size_t MS_OFF  = X_ELEMS;
static const size_t HB_OFF  = MS_OFF + 2048;
static const size_t FL_OFF  = HB_OFF + 2ull * B_DIM * H_DIM;
static const size_t GO_OFF  = FL_OFF + 256 * 32;          // int-sized elems

// ============ K1: column sums of w_hh per LN group ============
__global__ __launch_bounds__(256) void k_colsum(const float* __restrict__ w_hh,
                                                float* __restrict__ msum)
{
    int k  = blockIdx.x * 256 + threadIdx.x;   // gridDim.x == 4
    int rc = blockIdx.y;                       // 0..11 row chunks of 256
    const float* p = w_hh + (size_t)rc * 256 * H_DIM + k;
    float s = 0.f;
    #pragma unroll 8
    for (int r = 0; r < 256; ++r) s += p[(size_t)r * H_DIM];
    atomicAdd(&msum[(rc < 8 ? 0 : 1) * H_DIM + k], s);
}

// ============ K2: proj = xs @ w_ih^T , f32, out layout [T][B][3072] ============
#define BM 128
#define BN 64
#define BK 32
__global__ __launch_bounds__(256) void k_gemm(const float* __restrict__ A,
                                              const float* __restrict__ Bw,
                                              float* __restrict__ X)
{
    __shared__ float As[BK][BM + 4];
    __shared__ float Bs[BK][BN + 4];
    int n0 = blockIdx.x * BN;
    int m0 = blockIdx.y * BM;
    int tid = threadIdx.x;
    int tx = tid & 15, ty = tid >> 4;
    float acc[8][4];
    #pragma unroll
    for (int i = 0; i < 8; ++i)
        #pragma unroll
        for (int j = 0; j < 4; ++j) acc[i][j] = 0.f;

    for (int k0 = 0; k0 < 1024; k0 += BK) {
        #pragma unroll
        for (int p = 0; p < 4; ++p) {
            int id = tid + p * 256;
            int r = id >> 3, c4 = (id & 7) * 4;
            float4 v = *(const float4*)&A[(size_t)(m0 + r) * 1024 + k0 + c4];
            As[c4 + 0][r] = v.x; As[c4 + 1][r] = v.y;
            As[c4 + 2][r] = v.z; As[c4 + 3][r] = v.w;
        }
        #pragma unroll
        for (int p = 0; p < 2; ++p) {
            int id = tid + p * 256;
            int r = id >> 3, c4 = (id & 7) * 4;
            float4 v = *(const float4*)&Bw[(size_t)(n0 + r) * 1024 + k0 + c4];
            Bs[c4 + 0][r] = v.x; Bs[c4 + 1][r] = v.y;
            Bs[c4 + 2][r] = v.z; Bs[c4 + 3][r] = v.w;
        }
        __syncthreads();
        #pragma unroll
        for (int kk = 0; kk < BK; ++kk) {
            float4 a0 = *(const float4*)&As[kk][ty * 8];
            float4 a1 = *(const float4*)&As[kk][ty * 8 + 4];
            float4 b0 = *(const float4*)&Bs[kk][tx * 4];
            float a[8] = {a0.x, a0.y, a0.z, a0.w, a1.x, a1.y, a1.z, a1.w};
            float b[4] = {b0.x, b0.y, b0.z, b0.w};
            #pragma unroll
            for (int i = 0; i < 8; ++i)
                #pragma unroll
                for (int j = 0; j < 4; ++j) acc[i][j] += a[i] * b[j];
        }
        __syncthreads();
    }
    #pragma unroll
    for (int i = 0; i < 8; ++i) {
        int m = m0 + ty * 8 + i;
        int tt = m & (T_DIM - 1), bb = m >> 11;
        float4 v = make_float4(acc[i][0], acc[i][1], acc[i][2], acc[i][3]);
        *(float4*)&X[((size_t)tt * B_DIM + bb) * C3 + n0 + tx * 4] = v;
    }
}

// ============ K3: in-place _ln_x per 3072-row ============
__device__ __forceinline__ float block_sum_256(float v, float* sb)
{
    #pragma unroll
    for (int o = 32; o > 0; o >>= 1) v += __shfl_down(v, o, 64);
    int lane = threadIdx.x & 63, wid = threadIdx.x >> 6;
    if (lane == 0) sb[wid] = v;
    __syncthreads();
    float r = (sb[0] + sb[1]) + (sb[2] + sb[3]);
    __syncthreads();
    return r;
}

__global__ __launch_bounds__(256) void k_ln(float* __restrict__ X,
                                            const float* __restrict__ gamma,
                                            const float* __restrict__ beta)
{
    __shared__ float sb[4];
    float* p = X + (size_t)blockIdx.x * C3;
    int tid = threadIdx.x;
    float v[8], w[4];
    float4 t0 = *(float4*)&p[tid * 8];
    float4 t1 = *(float4*)&p[tid * 8 + 4];
    v[0]=t0.x; v[1]=t0.y; v[2]=t0.z; v[3]=t0.w;
    v[4]=t1.x; v[5]=t1.y; v[6]=t1.z; v[7]=t1.w;
    float4 t2 = *(float4*)&p[2048 + tid * 4];
    w[0]=t2.x; w[1]=t2.y; w[2]=t2.z; w[3]=t2.w;

    float s = 0.f;
    #pragma unroll
    for (int i = 0; i < 8; ++i) s += v[i];
    float mean = block_sum_256(s, sb) * (1.f / 2048.f);
    float ss = 0.f;
    #pragma unroll
    for (int i = 0; i < 8; ++i) { float d = v[i] - mean; ss += d * d; }
    float inv = rsqrtf(block_sum_256(ss, sb) * (1.f / 2047.f));
    #pragma unroll
    for (int i = 0; i < 8; ++i) {
        int c = tid * 8 + i;
        v[i] = gamma[c] * (v[i] - mean) * inv + beta[c];
    }
    *(float4*)&p[tid * 8]     = make_float4(v[0], v[1], v[2], v[3]);
    *(float4*)&p[tid * 8 + 4] = make_float4(v[4], v[5], v[6], v[7]);

    float sn = (w[0] + w[1]) + (w[2] + w[3]);
    float mn = block_sum_256(sn, sb) * (1.f / 1024.f);
    float ssn = 0.f;
    #pragma unroll
    for (int i = 0; i < 4; ++i) { float d = w[i] - mn; ssn += d * d; }
    float invn = rsqrtf(block_sum_256(ssn, sb) * (1.f / 1023.f));
    #pragma unroll
    for (int i = 0; i < 4; ++i) {
        int c = 2048 + tid * 4 + i;
        w[i] = gamma[c] * (w[i] - mn) * invn + beta[c];
    }
    *(float4*)&p[2048 + tid * 4] = make_float4(w[0], w[1], w[2], w[3]);
}

// ============ K4: persistent weight-stationary scan ============
// 256 blocks x 1024 threads, 1 block/CU.
// h ping-pong: agent-scope RELAXED atomics (LLC-coherent, no L2 inv/wb).
// Barrier: contention-free flag tree, ZERO RMWs, <=1 poller per 128B line:
//   arrival: block bid RELEASE-stores flags[bid]=t+1 (drains its h stores)
//   block 0: thread i polls flags[i] (1 poller/line), syncs, stores go[i]=t+1
//   block bid: tid0 polls go[bid] (1 poller/line), syncs.
__device__ __forceinline__ int swz(int k) { return k ^ (((k >> 4) & 7) << 2); }

#define FMA_E(comp, e)                                                      \
    { float w0_ = w[0][kq + e], w1_ = w[1][kq + e], w2_ = w[2][kq + e];     \
      acc[0][0] += w0_ * hv0.comp; acc[0][1] += w0_ * hv1.comp;             \
      acc[0][2] += w0_ * hv2.comp; acc[0][3] += w0_ * hv3.comp;             \
      acc[1][0] += w1_ * hv0.comp; acc[1][1] += w1_ * hv1.comp;             \
      acc[1][2] += w1_ * hv2.comp; acc[1][3] += w1_ * hv3.comp;             \
      acc[2][0] += w2_ * hv0.comp; acc[2][1] += w2_ * hv1.comp;             \
      acc[2][2] += w2_ * hv2.comp; acc[2][3] += w2_ * hv3.comp; }

__global__ __launch_bounds__(1024, 4) void k_scan(
    const float* __restrict__ X,
    const float* __restrict__ w_hh,
    const float* __restrict__ g_hh,
    const float* __restrict__ b_hh,
    const float* __restrict__ msum,
    const float* __restrict__ h0,
    float* __restrict__ hbuf,
    float* __restrict__ ys,
    float* __restrict__ hfin,
    int* __restrict__ flags,
    int* __restrict__ go)
{
    __shared__ float hs[16 * 1024];
    __shared__ float dotl[12][17];

    int tid = threadIdx.x;
    int bid = blockIdx.x;
    int cg = tid >> 8, bg = (tid >> 6) & 3, ks = tid & 63;
    int js = bid * 4;

    // ---- load W'' = gamma*(w_hh - colmean) into registers (once) ----
    float w[3][16];
    #pragma unroll
    for (int ci = 0; ci < 3; ++ci) {
        int lc = cg * 3 + ci;
        int gate = lc >> 2, jl = lc & 3;
        int c = gate * H_DIM + js + jl;
        int grp = (gate < 2) ? 0 : 1;
        float scale = grp ? (1.f / 1024.f) : (1.f / 2048.f);
        float gm = g_hh[c];
        const float* wr = w_hh + (size_t)c * H_DIM;
        #pragma unroll
        for (int q = 0; q < 16; ++q) {
            int k = ks * 16 + q;
            w[ci][q] = gm * (wr[k] - msum[grp * H_DIM + k] * scale);
        }
    }

    // gate-phase constants
    int bl = tid & 15, jl4 = tid >> 4;            // valid when tid < 64
    float br = 0.f, bz = 0.f, bn = 0.f;
    if (tid < 64) {
        br = b_hh[js + jl4];
        bz = b_hh[H_DIM + js + jl4];
        bn = b_hh[2 * H_DIM + js + jl4];
    }

    for (int t = 0; t < T_DIM; ++t) {
        // X[t] prefetch (normal cached loads; latency hidden under stage+dot)
        float xr = 0.f, xz = 0.f, xn = 0.f;
        if (tid < 64) {
            const float* xp = X + ((size_t)t * B_DIM + bl) * C3 + js + jl4;
            xr = xp[0]; xz = xp[H_DIM]; xn = xp[2 * H_DIM];
        }

        // ---- stage h into LDS (agent-atomic loads, swizzled scalar writes) ----
        const float* h_in = t ? (hbuf + (size_t)(t & 1) * B_DIM * H_DIM) : h0;
        int sk = swz(tid);
        #pragma unroll
        for (int q = 0; q < 16; ++q) {
            float v = __hip_atomic_load((float*)(h_in + q * H_DIM + tid),
                                        __ATOMIC_RELAXED,
                                        __HIP_MEMORY_SCOPE_AGENT);
            hs[q * H_DIM + sk] = v;
        }
        __syncthreads();

        // ---- partial dots: 3ch x 4b x 16k ----
        float acc[3][4];
        #pragma unroll
        for (int i = 0; i < 3; ++i)
            #pragma unroll
            for (int j = 0; j < 4; ++j) acc[i][j] = 0.f;

        #pragma unroll
        for (int kk = 0; kk < 4; ++kk) {
            int kq = kk * 4;
            int kw = (ks * 16 + kq) ^ ((ks & 7) << 2);
            float4 hv0 = *(const float4*)&hs[(bg * 4 + 0) * H_DIM + kw];
            float4 hv1 = *(const float4*)&hs[(bg * 4 + 1) * H_DIM + kw];
            float4 hv2 = *(const float4*)&hs[(bg * 4 + 2) * H_DIM + kw];
            float4 hv3 = *(const float4*)&hs[(bg * 4 + 3) * H_DIM + kw];
            FMA_E(x, 0) FMA_E(y, 1) FMA_E(z, 2) FMA_E(w, 3)
        }

        // ---- butterfly reduce over ks lanes ----
        #pragma unroll
        for (int m = 1; m <= 32; m <<= 1)
            #pragma unroll
            for (int ci = 0; ci < 3; ++ci)
                #pragma unroll
                for (int bi = 0; bi < 4; ++bi)
                    acc[ci][bi] += __shfl_xor(acc[ci][bi], m, 64);
        if (ks == 0) {
            #pragma unroll
            for (int ci = 0; ci < 3; ++ci)
                #pragma unroll
                for (int bi = 0; bi < 4; ++bi)
                    dotl[cg * 3 + ci][bg * 4 + bi] = acc[ci][bi];
        }
        __syncthreads();

        // ---- gates: 4 j x 16 b (all in wave 0) ----
        float* h_out = hbuf + (size_t)((t + 1) & 1) * B_DIM * H_DIM;
        if (tid < 64) {
            int j = js + jl4;
            float dr = dotl[jl4][bl] + br;
            float dz = dotl[4 + jl4][bl] + bz;
            float dn = dotl[8 + jl4][bl] + bn;
            float r = 1.f / (1.f + __expf(-(xr + dr)));
            float z = 1.f / (1.f + __expf(-(xz + dz)));
            float n = tanhf(xn + r * dn);
            float hold = hs[bl * H_DIM + swz(j)];
            float hnew = (1.f - z) * n + z * hold;
            __hip_atomic_store(&h_out[(size_t)bl * H_DIM + j], hnew,
                               __ATOMIC_RELAXED, __HIP_MEMORY_SCOPE_AGENT);
            ys[((size_t)bl * T_DIM + t) * H_DIM + j] = hnew;
            if (t == T_DIM - 1) hfin[(size_t)bl * H_DIM + j] = hnew;
        }

        // ---- arrival: release-store own flag (drains wave-0 h stores) ----
        if (tid == 0)
            __hip_atomic_store(&flags[bid * 32], t + 1, __ATOMIC_RELEASE,
                               __HIP_MEMORY_SCOPE_AGENT);

        // ---- flag-tree barrier (zero RMW, <=1 poller per line) ----
        if (bid == 0) {
            if (tid < NBLK) {
                while (__hip_atomic_load(&flags[tid * 32], __ATOMIC_RELAXED,
                                         __HIP_MEMORY_SCOPE_AGENT) < t + 1)
                    __builtin_amdgcn_s_sleep(1);
            }
            __syncthreads();   // all arrivals observed
            if (tid < NBLK)
                __hip_atomic_store(&go[tid * 32], t + 1, __ATOMIC_RELAXED,
                                   __HIP_MEMORY_SCOPE_AGENT);
        } else {
            if (tid == 0) {
                while (__hip_atomic_load(&go[bid * 32], __ATOMIC_RELAXED,
                                         __HIP_MEMORY_SCOPE_AGENT) < t + 1)
                    __builtin_amdgcn_s_sleep(1);
            }
            __syncthreads();   // block released; h(t+1) globally visible
        }
    }
}

extern "C" void kernel_launch(void* const* d_in, const int* in_sizes, int n_in,
                              void* d_out, int out_size, void* d_ws, size_t ws_size,
                              hipStream_t stream)
{
    (void)in_sizes; (void)n_in; (void)out_size; (void)ws_size;
    const float* xs   = (const float*)d_in[0];
    const float* h0   = (const float*)d_in[1];
    const float* w_ih = (const float*)d_in[2];
    const float* w_hh = (const float*)d_in[3];
    const float* b_ih = (const float*)d_in[4];
    const float* b_hh = (const float*)d_in[5];
    const float* g_ih = (const float*)d_in[6];
    const float* g_hh = (const float*)d_in[7];
    float* out = (float*)d_out;
    float* ws  = (float*)d_ws;

    float* x     = ws;
    float* msum  = ws + MS_OFF;
    float* hbuf  = ws + HB_OFF;
    int*   flags = (int*)(ws + FL_OFF);
    int*   go    = (int*)(ws + GO_OFF);

    // zero msum + hbuf + flags + go (ws is re-poisoned before every call)
    hipMemsetAsync(msum, 0,
                   (2048 + 2ull * B_DIM * H_DIM + 2 * 256 * 32) * sizeof(float),
                   stream);
    k_colsum<<<dim3(4, 12), 256, 0, stream>>>(w_hh, msum);
    k_gemm<<<dim3(48, 256), 256, 0, stream>>>(xs, w_ih, x);
    k_ln<<<T_DIM * B_DIM, 256, 0, stream>>>(x, g_ih, b_ih);
    k_scan<<<NBLK, 1024, 0, stream>>>(x, w_hh, g_hh, b_hh, msum, h0, hbuf,
                                      out, out + (size_t)B_DIM * T_DIM * H_DIM,
                                      flags, go);
}

// Round 10
// 30310.370 us; speedup vs baseline: 2.5856x; 1.9436x over previous
//
#include <hip/hip_runtime.h>

#define T_DIM 2048
#define B_DIM 16
#define H_DIM 1024
#define C3    3072
#define NBLK  256

typedef float f4 __attribute__((ext_vector_type(4)));

// ---------------- ws layout (float elements) ----------------
// x     : [T][B][3072]  normalized input projections (384 MB)
// msum  : [2][1024]     column sums of w_hh groups
// hbuf  : [2][16][1024] ping-pong hidden state (LLC-coherent sc0sc1 access)
// flags : 256 slots x 32 ints (128B/slot)  per-block arrival stamps
static const size_t X_ELEMS = (size_t)T_DIM * B_DIM * C3;
static const size_t MS_OFF  = X_ELEMS;
static const size_t HB_OFF  = MS_OFF + 2048;
static const size_t FL_OFF  = HB_OFF + 2ull * B_DIM * H_DIM;

// ============ K1: column sums of w_hh per LN group ============
__global__ __launch_bounds__(256) void k_colsum(const float* __restrict__ w_hh,
                                                float* __restrict__ msum)
{
    int k  = blockIdx.x * 256 + threadIdx.x;   // gridDim.x == 4
    int rc = blockIdx.y;                       // 0..11 row chunks of 256
    const float* p = w_hh + (size_t)rc * 256 * H_DIM + k;
    float s = 0.f;
    #pragma unroll 8
    for (int r = 0; r < 256; ++r) s += p[(size_t)r * H_DIM];
    atomicAdd(&msum[(rc < 8 ? 0 : 1) * H_DIM + k], s);
}

// ============ K2: proj = xs @ w_ih^T , f32, out layout [T][B][3072] ============
#define BM 128
#define BN 64
#define BK 32
__global__ __launch_bounds__(256) void k_gemm(const float* __restrict__ A,
                                              const float* __restrict__ Bw,
                                              float* __restrict__ X)
{
    __shared__ float As[BK][BM + 4];
    __shared__ float Bs[BK][BN + 4];
    int n0 = blockIdx.x * BN;
    int m0 = blockIdx.y * BM;
    int tid = threadIdx.x;
    int tx = tid & 15, ty = tid >> 4;
    float acc[8][4];
    #pragma unroll
    for (int i = 0; i < 8; ++i)
        #pragma unroll
        for (int j = 0; j < 4; ++j) acc[i][j] = 0.f;

    for (int k0 = 0; k0 < 1024; k0 += BK) {
        #pragma unroll
        for (int p = 0; p < 4; ++p) {
            int id = tid + p * 256;
            int r = id >> 3, c4 = (id & 7) * 4;
            float4 v = *(const float4*)&A[(size_t)(m0 + r) * 1024 + k0 + c4];
            As[c4 + 0][r] = v.x; As[c4 + 1][r] = v.y;
            As[c4 + 2][r] = v.z; As[c4 + 3][r] = v.w;
        }
        #pragma unroll
        for (int p = 0; p < 2; ++p) {
            int id = tid + p * 256;
            int r = id >> 3, c4 = (id & 7) * 4;
            float4 v = *(const float4*)&Bw[(size_t)(n0 + r) * 1024 + k0 + c4];
            Bs[c4 + 0][r] = v.x; Bs[c4 + 1][r] = v.y;
            Bs[c4 + 2][r] = v.z; Bs[c4 + 3][r] = v.w;
        }
        __syncthreads();
        #pragma unroll
        for (int kk = 0; kk < BK; ++kk) {
            float4 a0 = *(const float4*)&As[kk][ty * 8];
            float4 a1 = *(const float4*)&As[kk][ty * 8 + 4];
            float4 b0 = *(const float4*)&Bs[kk][tx * 4];
            float a[8] = {a0.x, a0.y, a0.z, a0.w, a1.x, a1.y, a1.z, a1.w};
            float b[4] = {b0.x, b0.y, b0.z, b0.w};
            #pragma unroll
            for (int i = 0; i < 8; ++i)
                #pragma unroll
                for (int j = 0; j < 4; ++j) acc[i][j] += a[i] * b[j];
        }
        __syncthreads();
    }
    #pragma unroll
    for (int i = 0; i < 8; ++i) {
        int m = m0 + ty * 8 + i;
        int tt = m & (T_DIM - 1), bb = m >> 11;
        float4 v = make_float4(acc[i][0], acc[i][1], acc[i][2], acc[i][3]);
        *(float4*)&X[((size_t)tt * B_DIM + bb) * C3 + n0 + tx * 4] = v;
    }
}

// ============ K3: in-place _ln_x per 3072-row ============
__device__ __forceinline__ float block_sum_256(float v, float* sb)
{
    #pragma unroll
    for (int o = 32; o > 0; o >>= 1) v += __shfl_down(v, o, 64);
    int lane = threadIdx.x & 63, wid = threadIdx.x >> 6;
    if (lane == 0) sb[wid] = v;
    __syncthreads();
    float r = (sb[0] + sb[1]) + (sb[2] + sb[3]);
    __syncthreads();
    return r;
}

__global__ __launch_bounds__(256) void k_ln(float* __restrict__ X,
                                            const float* __restrict__ gamma,
                                            const float* __restrict__ beta)
{
    __shared__ float sb[4];
    float* p = X + (size_t)blockIdx.x * C3;
    int tid = threadIdx.x;
    float v[8], w[4];
    float4 t0 = *(float4*)&p[tid * 8];
    float4 t1 = *(float4*)&p[tid * 8 + 4];
    v[0]=t0.x; v[1]=t0.y; v[2]=t0.z; v[3]=t0.w;
    v[4]=t1.x; v[5]=t1.y; v[6]=t1.z; v[7]=t1.w;
    float4 t2 = *(float4*)&p[2048 + tid * 4];
    w[0]=t2.x; w[1]=t2.y; w[2]=t2.z; w[3]=t2.w;

    float s = 0.f;
    #pragma unroll
    for (int i = 0; i < 8; ++i) s += v[i];
    float mean = block_sum_256(s, sb) * (1.f / 2048.f);
    float ss = 0.f;
    #pragma unroll
    for (int i = 0; i < 8; ++i) { float d = v[i] - mean; ss += d * d; }
    float inv = rsqrtf(block_sum_256(ss, sb) * (1.f / 2047.f));
    #pragma unroll
    for (int i = 0; i < 8; ++i) {
        int c = tid * 8 + i;
        v[i] = gamma[c] * (v[i] - mean) * inv + beta[c];
    }
    *(float4*)&p[tid * 8]     = make_float4(v[0], v[1], v[2], v[3]);
    *(float4*)&p[tid * 8 + 4] = make_float4(v[4], v[5], v[6], v[7]);

    float sn = (w[0] + w[1]) + (w[2] + w[3]);
    float mn = block_sum_256(sn, sb) * (1.f / 1024.f);
    float ssn = 0.f;
    #pragma unroll
    for (int i = 0; i < 4; ++i) { float d = w[i] - mn; ssn += d * d; }
    float invn = rsqrtf(block_sum_256(ssn, sb) * (1.f / 1023.f));
    #pragma unroll
    for (int i = 0; i < 4; ++i) {
        int c = 2048 + tid * 4 + i;
        w[i] = gamma[c] * (w[i] - mn) * invn + beta[c];
    }
    *(float4*)&p[2048 + tid * 4] = make_float4(w[0], w[1], w[2], w[3]);
}

// ============ K4: persistent weight-stationary scan ============
// 256 blocks x 1024 threads, 1 block/CU.
// h exchange: sc0sc1 (L2-bypass, LLC-coherent) COALESCED dwordx4 loads;
//   h_new stores are relaxed agent atomics (write-through LLC). No fences,
//   no L2 inv/wb anywhere in the loop.
// Barrier: single-hop all-poll-all. Arrival = s_waitcnt vmcnt(0) (drains h
//   stores to LLC) + relaxed flag store; every block's tid<256 polls all 256
//   flag lines (1 line/thread), __syncthreads. Monotone stamps, no reset.
__device__ __forceinline__ int swz(int k) { return k ^ (((k >> 4) & 7) << 2); }

#define FMA_E(comp, e)                                                      \
    { float w0_ = w[0][kq + e], w1_ = w[1][kq + e], w2_ = w[2][kq + e];     \
      acc[0][0] += w0_ * hv0.comp; acc[0][1] += w0_ * hv1.comp;             \
      acc[0][2] += w0_ * hv2.comp; acc[0][3] += w0_ * hv3.comp;             \
      acc[1][0] += w1_ * hv0.comp; acc[1][1] += w1_ * hv1.comp;             \
      acc[1][2] += w1_ * hv2.comp; acc[1][3] += w1_ * hv3.comp;             \
      acc[2][0] += w2_ * hv0.comp; acc[2][1] += w2_ * hv1.comp;             \
      acc[2][2] += w2_ * hv2.comp; acc[2][3] += w2_ * hv3.comp; }

__global__ __launch_bounds__(1024, 4) void k_scan(
    const float* __restrict__ X,
    const float* __restrict__ w_hh,
    const float* __restrict__ g_hh,
    const float* __restrict__ b_hh,
    const float* __restrict__ msum,
    const float* __restrict__ h0,
    float* __restrict__ hbuf,
    float* __restrict__ ys,
    float* __restrict__ hfin,
    int* __restrict__ flags)
{
    __shared__ float hs[16 * 1024];
    __shared__ float dotl[12][17];

    int tid = threadIdx.x;
    int bid = blockIdx.x;
    int cg = tid >> 8, bg = (tid >> 6) & 3, ks = tid & 63;
    int js = bid * 4;

    // ---- load W'' = gamma*(w_hh - colmean) into registers (once) ----
    float w[3][16];
    #pragma unroll
    for (int ci = 0; ci < 3; ++ci) {
        int lc = cg * 3 + ci;
        int gate = lc >> 2, jl = lc & 3;
        int c = gate * H_DIM + js + jl;
        int grp = (gate < 2) ? 0 : 1;
        float scale = grp ? (1.f / 1024.f) : (1.f / 2048.f);
        float gm = g_hh[c];
        const float* wr = w_hh + (size_t)c * H_DIM;
        #pragma unroll
        for (int q = 0; q < 16; ++q) {
            int k = ks * 16 + q;
            w[ci][q] = gm * (wr[k] - msum[grp * H_DIM + k] * scale);
        }
    }

    // gate-phase constants
    int bl = tid & 15, jl4 = tid >> 4;            // valid when tid < 64
    float br = 0.f, bz = 0.f, bn = 0.f;
    if (tid < 64) {
        br = b_hh[js + jl4];
        bz = b_hh[H_DIM + js + jl4];
        bn = b_hh[2 * H_DIM + js + jl4];
    }

    // stage-phase constants: thread covers 16 consecutive floats of row hrow.
    // kbase % 16 == 0, swizzle mask M=(ks&7)<<2 touches bits 2-4 only, so for
    // i in {0,4,8,12}: swz(kbase+i) = swz(kbase) ^ i   (XOR, NOT add!).
    int hrow = tid >> 6;                   // wave w stages h row w
    int kbase = (tid & 63) * 16;
    int sbase = hrow * H_DIM + swz(kbase);

    for (int t = 0; t < T_DIM; ++t) {
        // X[t] prefetch (normal cached loads; latency hidden under stage+dot)
        float xr = 0.f, xz = 0.f, xn = 0.f;
        if (tid < 64) {
            const float* xp = X + ((size_t)t * B_DIM + bl) * C3 + js + jl4;
            xr = xp[0]; xz = xp[H_DIM]; xn = xp[2 * H_DIM];
        }

        // ---- stage h into LDS: coalesced LLC-coherent 64B/thread ----
        const float* hp = (t ? hbuf + (size_t)(t & 1) * B_DIM * H_DIM : h0)
                          + (size_t)tid * 16;
        f4 va, vb, vc, vd;
        asm volatile(
            "global_load_dwordx4 %0, %4, off sc0 sc1\n\t"
            "global_load_dwordx4 %1, %4, off offset:16 sc0 sc1\n\t"
            "global_load_dwordx4 %2, %4, off offset:32 sc0 sc1\n\t"
            "global_load_dwordx4 %3, %4, off offset:48 sc0 sc1\n\t"
            "s_waitcnt vmcnt(0)"
            : "=&v"(va), "=&v"(vb), "=&v"(vc), "=&v"(vd)
            : "v"(hp) : "memory");
        *(f4*)&hs[sbase]       = va;      // elems kbase+0..3  -> swz(kbase)^0
        *(f4*)&hs[sbase ^ 4]   = vb;      // elems kbase+4..7  -> swz(kbase)^4
        *(f4*)&hs[sbase ^ 8]   = vc;      // elems kbase+8..11 -> swz(kbase)^8
        *(f4*)&hs[sbase ^ 12]  = vd;      // elems kbase+12..15-> swz(kbase)^12
        __syncthreads();

        // ---- partial dots: 3ch x 4b x 16k ----
        float acc[3][4];
        #pragma unroll
        for (int i = 0; i < 3; ++i)
            #pragma unroll
            for (int j = 0; j < 4; ++j) acc[i][j] = 0.f;

        #pragma unroll
        for (int kk = 0; kk < 4; ++kk) {
            int kq = kk * 4;
            int kw = (ks * 16 + kq) ^ ((ks & 7) << 2);
            float4 hv0 = *(const float4*)&hs[(bg * 4 + 0) * H_DIM + kw];
            float4 hv1 = *(const float4*)&hs[(bg * 4 + 1) * H_DIM + kw];
            float4 hv2 = *(const float4*)&hs[(bg * 4 + 2) * H_DIM + kw];
            float4 hv3 = *(const float4*)&hs[(bg * 4 + 3) * H_DIM + kw];
            FMA_E(x, 0) FMA_E(y, 1) FMA_E(z, 2) FMA_E(w, 3)
        }

        // ---- butterfly reduce over ks lanes ----
        #pragma unroll
        for (int m = 1; m <= 32; m <<= 1)
            #pragma unroll
            for (int ci = 0; ci < 3; ++ci)
                #pragma unroll
                for (int bi = 0; bi < 4; ++bi)
                    acc[ci][bi] += __shfl_xor(acc[ci][bi], m, 64);
        if (ks == 0) {
            #pragma unroll
            for (int ci = 0; ci < 3; ++ci)
                #pragma unroll
                for (int bi = 0; bi < 4; ++bi)
                    dotl[cg * 3 + ci][bg * 4 + bi] = acc[ci][bi];
        }
        __syncthreads();

        // ---- gates: 4 j x 16 b (all in wave 0) ----
        float* h_out = hbuf + (size_t)((t + 1) & 1) * B_DIM * H_DIM;
        if (tid < 64) {
            int j = js + jl4;
            float dr = dotl[jl4][bl] + br;
            float dz = dotl[4 + jl4][bl] + bz;
            float dn = dotl[8 + jl4][bl] + bn;
            float r = 1.f / (1.f + __expf(-(xr + dr)));
            float z = 1.f / (1.f + __expf(-(xz + dz)));
            float n = tanhf(xn + r * dn);
            float hold = hs[bl * H_DIM + swz(j)];
            float hnew = (1.f - z) * n + z * hold;
            __hip_atomic_store(&h_out[(size_t)bl * H_DIM + j], hnew,
                               __ATOMIC_RELAXED, __HIP_MEMORY_SCOPE_AGENT);
            ys[((size_t)bl * T_DIM + t) * H_DIM + j] = hnew;
            if (t == T_DIM - 1) hfin[(size_t)bl * H_DIM + j] = hnew;
            // drain wave-0's h stores to the LLC before the flag publishes
            asm volatile("s_waitcnt vmcnt(0)" ::: "memory");
        }
        if (tid == 0)
            __hip_atomic_store(&flags[bid * 32], t + 1, __ATOMIC_RELAXED,
                               __HIP_MEMORY_SCOPE_AGENT);

        // ---- single-hop all-poll-all barrier ----
        if (tid < NBLK) {
            while (__hip_atomic_load(&flags[tid * 32], __ATOMIC_RELAXED,
                                     __HIP_MEMORY_SCOPE_AGENT) < t + 1)
                __builtin_amdgcn_s_sleep(1);
        }
        __syncthreads();
    }
}

extern "C" void kernel_launch(void* const* d_in, const int* in_sizes, int n_in,
                              void* d_out, int out_size, void* d_ws, size_t ws_size,
                              hipStream_t stream)
{
    (void)in_sizes; (void)n_in; (void)out_size; (void)ws_size;
    const float* xs   = (const float*)d_in[0];
    const float* h0   = (const float*)d_in[1];
    const float* w_ih = (const float*)d_in[2];
    const float* w_hh = (const float*)d_in[3];
    const float* b_ih = (const float*)d_in[4];
    const float* b_hh = (const float*)d_in[5];
    const float* g_ih = (const float*)d_in[6];
    const float* g_hh = (const float*)d_in[7];
    float* out = (float*)d_out;
    float* ws  = (float*)d_ws;

    float* x     = ws;
    float* msum  = ws + MS_OFF;
    float* hbuf  = ws + HB_OFF;
    int*   flags = (int*)(ws + FL_OFF);

    // zero msum + hbuf + flags (ws is re-poisoned before every call)
    hipMemsetAsync(msum, 0,
                   (2048 + 2ull * B_DIM * H_DIM + 256 * 32) * sizeof(float),
                   stream);
    k_colsum<<<dim3(4, 12), 256, 0, stream>>>(w_hh, msum);
    k_gemm<<<dim3(48, 256), 256, 0, stream>>>(xs, w_ih, x);
    k_ln<<<T_DIM * B_DIM, 256, 0, stream>>>(x, g_ih, b_ih);
    k_scan<<<NBLK, 1024, 0, stream>>>(x, w_hh, g_hh, b_hh, msum, h0, hbuf,
                                      out, out + (size_t)B_DIM * T_DIM * H_DIM,
                                      flags);
}